// Round 15
// baseline (35.570 us; speedup 1.0000x reference)
//
#include <hip/hip_runtime.h>
#include <math.h>

#define LB __launch_bounds__(256)

// scales: 0:{C=48,H=96,N=9216} 1:{96,48,2304} 2:{192,24,576} 3:{384,12,144}, B=2
// pixel-slot offsets (b-major within scale): {0, 18432, 23040, 24192}, total 24480
#define NSLOT 24480
#define MT 28        // Taylor terms m=0..27 of exp(q*k); 9*MT = 252 <= 256 threads
#define NMOM 252     // values per block: [m][j], j=0 -> d_m, j=1..8 -> M_m[j-1]
#define NBLK_Q 540   // qkvm grid
#define NSLICE 4     // momred row-slices per sb

typedef float f32x4 __attribute__((ext_vector_type(4)));

struct QkvmArgs {
  const float *x0, *x1, *x2, *x3;
  const float *w0, *w1, *w2, *w3;
  const float *c0, *c1, *c2, *c3;
  const float *wq[4], *bq[4], *wk[4], *bk[4], *wv[4], *bv[4];
  float *P, *Q;
  float *MOMP;   // [NBLK_Q][NMOM] per-block moment partials (atomic-free, deterministic)
};

// tid = pxl*CG + cg: a pixel's CG channel-groups are CONTIGUOUS LANES (one wave) ->
// cross-cg conv reduction via butterfly shfl_xor, no LDS round-trip, one less barrier.
// Weight staging reads wp linearly (coalesced), scatters transposed into LDS.
template<int CG>
__device__ __forceinline__ void qkvm_body(const QkvmArgs& a, const int scale,
    const int N, const int slotoff, const int rel,
    const float* __restrict__ xp, const float* __restrict__ wp, const float* __restrict__ bp,
    float* s_w, float* s_sm, float* s_kp, float* s_v) {
  constexpr int C = 12 * CG;
  constexpr int PX = 256 / CG;
  const int tid = threadIdx.x;
  const int cg = tid & (CG - 1);
  const int pxl = tid / CG;
  const int bpb = N / PX;
  const int b = rel / bpb, blk = rel - b*bpb;
  const int n = blk*PX + pxl;
  const float* xb = xp + (size_t)b*C*N + n;
  const int c0 = cg*12;
  float xv[12];
  #pragma unroll
  for (int cc = 0; cc < 12; ++cc) xv[cc] = xb[(size_t)(c0+cc)*N];

  // coalesced weight read, transposed LDS scatter: s_w[c*8+o] = wp[o*C+c]
  #pragma unroll
  for (int j = tid; j < 8*C; j += 256) { const int o = j / C, c = j - o*C; s_w[c*8 + o] = wp[j]; }
  if (tid >= 128 && tid < 192) { const int t = tid - 128; s_sm[32 + t] = a.wv[scale][(t & 7)*8 + (t >> 3)]; }
  if (tid < 8) {
    s_sm[tid]      = bp[tid];
    s_sm[8 + tid]  = a.wq[scale][tid];
    s_sm[16 + tid] = a.wk[scale][tid];
    s_sm[24 + tid] = a.bv[scale][tid];
  }
  if (tid == 96) { s_sm[96] = a.bq[scale][0]; s_sm[97] = a.bk[scale][0]; }
  __syncthreads();

  float p[8];
  #pragma unroll
  for (int o = 0; o < 8; ++o) p[o] = 0.f;
  #pragma unroll
  for (int cc = 0; cc < 12; ++cc) {
    const float x = xv[cc];
    #pragma unroll
    for (int o = 0; o < 8; ++o) p[o] = fmaf(s_w[(c0+cc)*8+o], x, p[o]);
  }
  // butterfly reduce across cg (contiguous lanes, within wave since 64 % CG == 0)
  #pragma unroll
  for (int off = 1; off < CG; off <<= 1) {
    #pragma unroll
    for (int o = 0; o < 8; ++o) p[o] += __shfl_xor(p[o], off);
  }

  if (cg == 0) {
    float pc[8];
    #pragma unroll
    for (int o = 0; o < 8; ++o) pc[o] = p[o] + s_sm[o];
    float q = s_sm[96], kv = s_sm[97];
    #pragma unroll
    for (int c = 0; c < 8; ++c) { q = fmaf(s_sm[8+c], pc[c], q); kv = fmaf(s_sm[16+c], pc[c], kv); }
    float v[8];
    #pragma unroll
    for (int o = 0; o < 8; ++o) v[o] = s_sm[24 + o];
    #pragma unroll
    for (int c = 0; c < 8; ++c) {
      const float pcc = pc[c];
      #pragma unroll
      for (int o = 0; o < 8; ++o) v[o] = fmaf(s_sm[32 + c*8 + o], pcc, v[o]);
    }
    const int g = slotoff + b*N + n;
    f32x4* Pp = (f32x4*)&a.P[(size_t)g*8];
    Pp[0] = (f32x4){pc[0], pc[1], pc[2], pc[3]};
    Pp[1] = (f32x4){pc[4], pc[5], pc[6], pc[7]};
    a.Q[g] = q;
    s_kp[pxl*MT] = 1.f;
    float pw = 1.f;
    #pragma unroll
    for (int m = 1; m < MT; ++m) { pw *= kv; s_kp[pxl*MT + m] = pw; }
    #pragma unroll
    for (int j = 0; j < 8; ++j) s_v[pxl*8 + j] = v[j];
  }
  __syncthreads();

  if (tid < NMOM) {
    const int m = tid / 9, j = tid - m*9;
    float a0=0.f, a1=0.f, a2=0.f, a3=0.f;   // 4 streams: shorter dependent chains
    if (j == 0) {
      #pragma unroll 4
      for (int e = 0; e < PX; e += 4) {
        a0 += s_kp[(e+0)*MT + m];
        a1 += s_kp[(e+1)*MT + m];
        a2 += s_kp[(e+2)*MT + m];
        a3 += s_kp[(e+3)*MT + m];
      }
    } else {
      #pragma unroll 4
      for (int e = 0; e < PX; e += 4) {
        a0 = fmaf(s_kp[(e+0)*MT + m], s_v[(e+0)*8 + (j-1)], a0);
        a1 = fmaf(s_kp[(e+1)*MT + m], s_v[(e+1)*8 + (j-1)], a1);
        a2 = fmaf(s_kp[(e+2)*MT + m], s_v[(e+2)*8 + (j-1)], a2);
        a3 = fmaf(s_kp[(e+3)*MT + m], s_v[(e+3)*8 + (j-1)], a3);
      }
    }
    a.MOMP[(size_t)blockIdx.x*NMOM + tid] = (a0 + a1) + (a2 + a3);
  }
}

// grid: 288 + 144 + 72 + 36 = 540 blocks
// sb block ranges: sb0:[0,144) sb1:[144,288) sb2:[288,360) sb3:[360,432)
//                  sb4:[432,468) sb5:[468,504) sb6:[504,522) sb7:[522,540)
__global__ LB void qkvm_kernel(QkvmArgs a) {
  __shared__ __align__(16) float s_w[3072];
  __shared__ __align__(16) float s_sm[104];
  __shared__ __align__(16) float s_kp[64*MT];
  __shared__ __align__(16) float s_v[64*8];
  const int bid = blockIdx.x;
  if (bid < 288)      qkvm_body<4> (a, 0, 9216, 0,     bid,     a.x0, a.w0, a.c0, s_w, s_sm, s_kp, s_v);
  else if (bid < 432) qkvm_body<8> (a, 1, 2304, 18432, bid-288, a.x1, a.w1, a.c1, s_w, s_sm, s_kp, s_v);
  else if (bid < 504) qkvm_body<16>(a, 2, 576,  23040, bid-432, a.x2, a.w2, a.c2, s_w, s_sm, s_kp, s_v);
  else                qkvm_body<32>(a, 3, 144,  24192, bid-504, a.x3, a.w3, a.c3, s_w, s_sm, s_kp, s_v);
}

// Reduce per-block partials: 8 sb x NSLICE row-slices = 32 blocks.
__global__ LB void momred_kernel(const float* __restrict__ MOMP, float* __restrict__ MOMQ) {
  const int sb = blockIdx.x / NSLICE, sl = blockIdx.x - sb*NSLICE;
  const int tid = threadIdx.x;
  if (tid >= NMOM) return;
  const int start[8] = {0, 144, 288, 360, 432, 468, 504, 522};
  const int cnt[8]   = {144, 144, 72, 72, 36, 36, 18, 18};
  const int r0 = start[sb] + (cnt[sb]*sl)/NSLICE;
  const int r1 = start[sb] + (cnt[sb]*(sl+1))/NSLICE;
  const float* bp = MOMP + (size_t)r0*NMOM + tid;
  const int c = r1 - r0;
  float a0=0.f,a1=0.f,a2=0.f,a3=0.f,a4=0.f,a5=0.f,a6=0.f,a7=0.f;
  int t = 0;
  for (; t + 8 <= c; t += 8) {
    a0 += bp[(size_t)(t+0)*NMOM];
    a1 += bp[(size_t)(t+1)*NMOM];
    a2 += bp[(size_t)(t+2)*NMOM];
    a3 += bp[(size_t)(t+3)*NMOM];
    a4 += bp[(size_t)(t+4)*NMOM];
    a5 += bp[(size_t)(t+5)*NMOM];
    a6 += bp[(size_t)(t+6)*NMOM];
    a7 += bp[(size_t)(t+7)*NMOM];
  }
  for (; t < c; ++t) a0 += bp[(size_t)t*NMOM];
  const float s = ((a0+a1)+(a2+a3)) + ((a4+a5)+(a6+a7));
  MOMQ[(size_t)blockIdx.x*NMOM + tid] = s;
}

// Taylor softmax eval at one slot: out8 = (sum t_m M_m)/(sum t_m d_m); y = P + bg + wg*out8.
__device__ __forceinline__ void taylor_eval(const float* __restrict__ mb, const float* __restrict__ wg,
                                            const float* __restrict__ bg8, const float q,
                                            const float* __restrict__ Pp, float* y) {
  float t = 1.f, den = 0.f;
  float num[8];
  #pragma unroll
  for (int c = 0; c < 8; ++c) num[c] = 0.f;
  #pragma unroll
  for (int m = 0; m < MT; ++m) {
    const f32x4 a0 = *(const f32x4*)&mb[m*12];
    const f32x4 a1 = *(const f32x4*)&mb[m*12 + 4];
    const f32x4 a2 = *(const f32x4*)&mb[m*12 + 8];
    den    = fmaf(t, a0.x, den);
    num[0] = fmaf(t, a0.y, num[0]); num[1] = fmaf(t, a0.z, num[1]); num[2] = fmaf(t, a0.w, num[2]);
    num[3] = fmaf(t, a1.x, num[3]); num[4] = fmaf(t, a1.y, num[4]); num[5] = fmaf(t, a1.z, num[5]);
    num[6] = fmaf(t, a1.w, num[6]); num[7] = fmaf(t, a2.x, num[7]);
    if (m + 1 < MT) t *= q * (1.f/(float)(m+1));
  }
  const float inv = 1.f/den;
  float o8[8];
  #pragma unroll
  for (int c = 0; c < 8; ++c) o8[c] = num[c]*inv;
  const f32x4 pA = *(const f32x4*)Pp;
  const f32x4 pB = *(const f32x4*)(Pp + 4);
  const float pv[8] = {pA.x, pA.y, pA.z, pA.w, pB.x, pB.y, pB.z, pB.w};
  #pragma unroll
  for (int o = 0; o < 8; ++o) {
    float s2 = pv[o] + bg8[o];
    #pragma unroll
    for (int c = 0; c < 8; ++c) s2 = fmaf(wg[o*8 + c], o8[c], s2);
    y[o] = s2;
  }
}

// Bilerp from LDS corner rows (3 rows stored per scale, row clamping baked in at store).
template<int HS>
__device__ __forceinline__ void bilerp_lds(float* zo, const float* __restrict__ sYb,
                                           const int r, const int h, const int w) {
  constexpr float inv = (float)HS/96.0f;
  const float sy = (h + 0.5f)*inv - 0.5f;
  const float sx = (w + 0.5f)*inv - 0.5f;
  const int iy0 = (int)floorf(sy); const float fy = sy - (float)iy0;
  const int ix0 = (int)floorf(sx); const float fx = sx - (float)ix0;
  const float syE = (2*r + 0.5f)*inv - 0.5f;
  const int ybase = (int)floorf(syE);
  const int ly0 = iy0 - ybase;                 // proven in {0,1}
  const int x0 = min(max(ix0, 0), HS-1), x1 = min(max(ix0 + 1, 0), HS-1);
  const float* p00 = &sYb[((ly0  )*HS + x0)*8];
  const float* p01 = &sYb[((ly0  )*HS + x1)*8];
  const float* p10 = &sYb[((ly0+1)*HS + x0)*8];
  const float* p11 = &sYb[((ly0+1)*HS + x1)*8];
  const float w00 = (1.f-fy)*(1.f-fx), w01 = (1.f-fy)*fx, w10 = fy*(1.f-fx), w11 = fy*fx;
  #pragma unroll
  for (int c = 0; c < 8; ++c)
    zo[c] = w00*p00[c] + w01*p01[c] + w10*p10[c] + w11*p11[c];
}

struct HFArgs {
  const float *Q, *P, *MOMQ;
  const float *wg0, *bg0, *wg1, *bg1, *wg2, *bg2;
  const float *wl0, *bl0, *bn_s, *bn_b, *bn_m, *bn_v, *wl1, *bl1;
  float *out;
};

// 96 blocks x 256 threads; block = (b, row-pair r): output rows 2r, 2r+1 of image b.
__global__ LB void headfin_kernel(HFArgs a) {
  __shared__ __align__(16) float smom[8*MT*12];   // 2688
  __shared__ __align__(16) float sY[2016];        // s1:[0,1152) s2:[1152,1728) s3:[1728,2016)
  __shared__ float swg[3][64], sbg[3][8];
  __shared__ float s_wl0[1024], s_wl1[608];
  __shared__ float s_bl0[32], s_sc[32], s_sh[32], s_bl1[19];
  const int tid = threadIdx.x;
  const int bid = blockIdx.x;
  const int b = bid / 48, r = bid - b*48;

  for (int i = tid; i < 1024; i += 256) s_wl0[i] = a.wl0[i];
  for (int i = tid; i < 608;  i += 256) s_wl1[i] = a.wl1[i];
  if (tid < 64) { swg[0][tid] = a.wg0[tid]; swg[1][tid] = a.wg1[tid]; swg[2][tid] = a.wg2[tid]; }
  if (tid < 8)  { sbg[0][tid] = a.bg0[tid]; sbg[1][tid] = a.bg1[tid]; sbg[2][tid] = a.bg2[tid]; }
  if (tid >= 64 && tid < 96) {
    const int c = tid - 64;
    s_bl0[c] = a.bl0[c];
    const float sc = a.bn_s[c] / sqrtf(a.bn_v[c] + 1e-5f);
    s_sc[c] = sc;
    s_sh[c] = a.bn_b[c] - a.bn_m[c]*sc;
  }
  if (tid >= 96 && tid < 115) s_bl1[tid - 96] = a.bl1[tid - 96];
  for (int i = tid; i < 8*MT*12; i += 256) {
    const int sbi = i / (MT*12), rr = i - sbi*(MT*12);
    const int m = rr / 12, j = rr - m*12;
    float s = 0.f;
    if (j < 9) {
      const float* qp = a.MOMQ + (size_t)sbi*NSLICE*NMOM + (m*9 + j);
      #pragma unroll
      for (int sl = 0; sl < NSLICE; ++sl) s += qp[(size_t)sl*NMOM];
    }
    smom[i] = s;
  }
  __syncthreads();

  // Phase A: corner evals (rows clamp(ybase+row_i) per scale)
  if (tid < 252) {
    int HS, soff, Nc, sb, widx, base, row_i, x;
    if (tid < 144)      { HS=48; soff=18432; Nc=2304; sb=2+b; widx=1; base=0;    row_i=tid/48;       x=tid-48*(tid/48); }
    else if (tid < 216) { const int t=tid-144; HS=24; soff=23040; Nc=576; sb=4+b; widx=2; base=1152; row_i=t/24; x=t-24*(t/24); }
    else                { const int t=tid-216; HS=12; soff=24192; Nc=144; sb=6+b; widx=1; base=1728; row_i=t/12; x=t-12*(t/12); }
    const float syE = (2*r + 0.5f)*(float)HS/96.0f - 0.5f;
    const int ybase = (int)floorf(syE);
    const int row = min(max(ybase + row_i, 0), HS-1);
    const int slot = soff + b*Nc + row*HS + x;
    float y[8];
    taylor_eval(&smom[sb*(MT*12)], swg[widx], sbg[widx], a.Q[slot], &a.P[(size_t)slot*8], y);
    #pragma unroll
    for (int c = 0; c < 8; ++c) sY[base + (row_i*HS + x)*8 + c] = y[c];
  }
  __syncthreads();

  // Phase B: 192 output pixels
  if (tid < 192) {
    const int hh = tid / 96;
    const int h = 2*r + hh;
    const int w = tid - 96*hh;
    const int n = h*96 + w;
    float z[32];
    {
      const int slot = b*9216 + n;
      taylor_eval(&smom[b*(MT*12)], swg[0], sbg[0], a.Q[slot], &a.P[(size_t)slot*8], z);
    }
    bilerp_lds<48>(z + 8,  &sY[0],    r, h, w);
    bilerp_lds<24>(z + 16, &sY[1152], r, h, w);
    bilerp_lds<12>(z + 24, &sY[1728], r, h, w);
    float o19[19];
    #pragma unroll
    for (int j = 0; j < 19; ++j) o19[j] = s_bl1[j];
    #pragma unroll 1
    for (int o = 0; o < 32; ++o) {
      float sA = s_bl0[o], sB = 0.f;
      #pragma unroll
      for (int c4 = 0; c4 < 4; ++c4) {
        const f32x4 wv = *(const f32x4*)&s_wl0[o*32 + c4*4];
        sA = fmaf(wv.x, z[c4*4+0], sA);
        sA = fmaf(wv.y, z[c4*4+1], sA);
        sA = fmaf(wv.z, z[c4*4+2], sA);
        sA = fmaf(wv.w, z[c4*4+3], sA);
      }
      #pragma unroll
      for (int c4 = 4; c4 < 8; ++c4) {
        const f32x4 wv = *(const f32x4*)&s_wl0[o*32 + c4*4];
        sB = fmaf(wv.x, z[c4*4+0], sB);
        sB = fmaf(wv.y, z[c4*4+1], sB);
        sB = fmaf(wv.z, z[c4*4+2], sB);
        sB = fmaf(wv.w, z[c4*4+3], sB);
      }
      const float t = fmaxf(fmaf(sA + sB, s_sc[o], s_sh[o]), 0.f);
      #pragma unroll
      for (int j = 0; j < 19; ++j) o19[j] = fmaf(s_wl1[j*32 + o], t, o19[j]);
    }
    #pragma unroll
    for (int j = 0; j < 19; ++j)
      a.out[((size_t)b*19 + j)*9216 + n] = o19[j];
  }
}

extern "C" void kernel_launch(void* const* d_in, const int* in_sizes, int n_in,
                              void* d_out, int out_size, void* d_ws, size_t ws_size,
                              hipStream_t stream) {
  (void)in_sizes; (void)n_in; (void)out_size; (void)ws_size;
  const float* wq[3]; const float* bq[3]; const float* wk[3]; const float* bk[3];
  const float* wv[3]; const float* bv[3]; const float* wg[3]; const float* bg[3];
  for (int i = 0; i < 3; ++i) {
    const int base = 12 + i*8;
    wq[i] = (const float*)d_in[base + 0]; bq[i] = (const float*)d_in[base + 1];
    wk[i] = (const float*)d_in[base + 2]; bk[i] = (const float*)d_in[base + 3];
    wv[i] = (const float*)d_in[base + 4]; bv[i] = (const float*)d_in[base + 5];
    wg[i] = (const float*)d_in[base + 6]; bg[i] = (const float*)d_in[base + 7];
  }
  const int m4[4] = {0, 1, 2, 1};   // scale -> cca index (scale3 reuses cca1, faithful)

  // workspace (floats): P[8N] Q[N] MOMP[540*252] MOMQ[32*252]  (~1.5 MB)
  float* ws = (float*)d_ws;
  float* P = ws;
  float* Q = P + (size_t)NSLOT*8;
  float* MOMP = Q + NSLOT;
  float* MOMQ = MOMP + (size_t)NBLK_Q*NMOM;

  QkvmArgs qa;
  qa.x0 = (const float*)d_in[0]; qa.x1 = (const float*)d_in[1];
  qa.x2 = (const float*)d_in[2]; qa.x3 = (const float*)d_in[3];
  qa.w0 = (const float*)d_in[4];  qa.c0 = (const float*)d_in[5];
  qa.w1 = (const float*)d_in[6];  qa.c1 = (const float*)d_in[7];
  qa.w2 = (const float*)d_in[8];  qa.c2 = (const float*)d_in[9];
  qa.w3 = (const float*)d_in[10]; qa.c3 = (const float*)d_in[11];
  for (int s = 0; s < 4; ++s) {
    qa.wq[s] = wq[m4[s]]; qa.bq[s] = bq[m4[s]];
    qa.wk[s] = wk[m4[s]]; qa.bk[s] = bk[m4[s]];
    qa.wv[s] = wv[m4[s]]; qa.bv[s] = bv[m4[s]];
  }
  qa.P = P; qa.Q = Q; qa.MOMP = MOMP;

  HFArgs ha;
  ha.Q = Q; ha.P = P; ha.MOMQ = MOMQ;
  ha.wg0 = wg[0]; ha.bg0 = bg[0];
  ha.wg1 = wg[1]; ha.bg1 = bg[1];
  ha.wg2 = wg[2]; ha.bg2 = bg[2];
  ha.wl0 = (const float*)d_in[36]; ha.bl0 = (const float*)d_in[37];
  ha.bn_s = (const float*)d_in[38]; ha.bn_b = (const float*)d_in[39];
  ha.bn_m = (const float*)d_in[40]; ha.bn_v = (const float*)d_in[41];
  ha.wl1 = (const float*)d_in[42]; ha.bl1 = (const float*)d_in[43];
  ha.out = (float*)d_out;

  qkvm_kernel<<<NBLK_Q, 256, 0, stream>>>(qa);
  momred_kernel<<<8*NSLICE, 256, 0, stream>>>(MOMP, MOMQ);
  headfin_kernel<<<96, 256, 0, stream>>>(ha);
}

// Round 16
// 32.358 us; speedup vs baseline: 1.0993x; 1.0993x over previous
//
#include <hip/hip_runtime.h>
#include <math.h>

#define LB __launch_bounds__(256)

// scales: 0:{C=48,H=96,N=9216} 1:{96,48,2304} 2:{192,24,576} 3:{384,12,144}, B=2
// pixel-slot offsets (b-major within scale): {0, 18432, 23040, 24192}, total 24480
#define NSLOT 24480
#define MT 28        // Taylor terms m=0..27 of exp(q*k); 9*MT = 252 <= 256 threads
#define MTP 29       // padded k-power stride (gcd(29,32)=1 -> no LDS bank conflict)
#define NMOM 252     // values per block: [m][j], j=0 -> d_m, j=1..8 -> M_m[j-1]
#define NBLK_Q 540   // qkvm grid
#define NSLICE 4     // momred row-slices per sb

typedef float f32x4 __attribute__((ext_vector_type(4)));

struct QkvmArgs {
  const float *x0, *x1, *x2, *x3;
  const float *w0, *w1, *w2, *w3;
  const float *c0, *c1, *c2, *c3;
  const float *wq[4], *bq[4], *wk[4], *bk[4], *wv[4], *bv[4];
  float *P, *Q;
  float *MOMP;   // [NBLK_Q][NMOM] per-block moment partials (atomic-free, deterministic)
};

// R13 layout: tid = cg*PX + px -> consecutive lanes are consecutive pixels (coalesced x loads).
// Weight staging reads wp LINEARLY (coalesced), scatters transposed into LDS.
template<int CG>
__device__ __forceinline__ void qkvm_body(const QkvmArgs& a, const int scale,
    const int N, const int slotoff, const int rel,
    const float* __restrict__ xp, const float* __restrict__ wp, const float* __restrict__ bp,
    float* s_w, float* s_sm, float* s_red, float* s_kp, float* s_v) {
  constexpr int C = 12 * CG;
  constexpr int PX = 256 / CG;
  const int tid = threadIdx.x;
  const int bpb = N / PX;
  const int b = rel / bpb, blk = rel - b*bpb;
  const int px = tid & (PX - 1), cg = tid / PX;
  const int n = blk*PX + px;
  const float* xb = xp + (size_t)b*C*N + n;
  const int c0 = cg*12;
  float xv[12];
  #pragma unroll
  for (int cc = 0; cc < 12; ++cc) xv[cc] = xb[(size_t)(c0+cc)*N];

  // coalesced weight read, transposed LDS scatter: s_w[c*8+o] = wp[o*C+c]
  #pragma unroll
  for (int j = tid; j < 8*C; j += 256) { const int o = j / C, c = j - o*C; s_w[c*8 + o] = wp[j]; }
  if (tid >= 128 && tid < 192) { const int t = tid - 128; s_sm[32 + t] = a.wv[scale][(t & 7)*8 + (t >> 3)]; }
  if (tid < 8) {
    s_sm[tid]      = bp[tid];
    s_sm[8 + tid]  = a.wq[scale][tid];
    s_sm[16 + tid] = a.wk[scale][tid];
    s_sm[24 + tid] = a.bv[scale][tid];
  }
  if (tid == 96) { s_sm[96] = a.bq[scale][0]; s_sm[97] = a.bk[scale][0]; }
  __syncthreads();

  float p[8];
  #pragma unroll
  for (int o = 0; o < 8; ++o) p[o] = 0.f;
  #pragma unroll
  for (int cc = 0; cc < 12; ++cc) {
    const float x = xv[cc];
    #pragma unroll
    for (int o = 0; o < 8; ++o) p[o] = fmaf(s_w[(c0+cc)*8+o], x, p[o]);
  }
  f32x4* sp = (f32x4*)&s_red[tid*8];
  sp[0] = (f32x4){p[0], p[1], p[2], p[3]};
  sp[1] = (f32x4){p[4], p[5], p[6], p[7]};
  __syncthreads();

  if (tid < PX) {
    float pc[8];
    #pragma unroll
    for (int o = 0; o < 8; ++o) {
      float s = s_sm[o];
      #pragma unroll
      for (int g = 0; g < CG; ++g) s += s_red[(g*PX + tid)*8 + o];
      pc[o] = s;
    }
    float q = s_sm[96], kv = s_sm[97];
    #pragma unroll
    for (int c = 0; c < 8; ++c) { q = fmaf(s_sm[8+c], pc[c], q); kv = fmaf(s_sm[16+c], pc[c], kv); }
    float v[8];
    #pragma unroll
    for (int o = 0; o < 8; ++o) v[o] = s_sm[24 + o];
    #pragma unroll
    for (int c = 0; c < 8; ++c) {
      const float pcc = pc[c];
      #pragma unroll
      for (int o = 0; o < 8; ++o) v[o] = fmaf(s_sm[32 + c*8 + o], pcc, v[o]);
    }
    const int g = slotoff + b*N + n;
    f32x4* Pp = (f32x4*)&a.P[(size_t)g*8];
    Pp[0] = (f32x4){pc[0], pc[1], pc[2], pc[3]};
    Pp[1] = (f32x4){pc[4], pc[5], pc[6], pc[7]};
    a.Q[g] = q;
    s_kp[tid*MTP] = 1.f;
    float pw = 1.f;
    #pragma unroll
    for (int m = 1; m < MT; ++m) { pw *= kv; s_kp[tid*MTP + m] = pw; }
    #pragma unroll
    for (int j = 0; j < 8; ++j) s_v[tid*8 + j] = v[j];
  }
  __syncthreads();

  if (tid < NMOM) {
    const int m = tid / 9, j = tid - m*9;
    float a0=0.f, a1=0.f, a2=0.f, a3=0.f;   // 4 streams: shorter dependent chains
    if (j == 0) {
      #pragma unroll 4
      for (int e = 0; e < PX; e += 4) {
        a0 += s_kp[(e+0)*MTP + m];
        a1 += s_kp[(e+1)*MTP + m];
        a2 += s_kp[(e+2)*MTP + m];
        a3 += s_kp[(e+3)*MTP + m];
      }
    } else {
      #pragma unroll 4
      for (int e = 0; e < PX; e += 4) {
        a0 = fmaf(s_kp[(e+0)*MTP + m], s_v[(e+0)*8 + (j-1)], a0);
        a1 = fmaf(s_kp[(e+1)*MTP + m], s_v[(e+1)*8 + (j-1)], a1);
        a2 = fmaf(s_kp[(e+2)*MTP + m], s_v[(e+2)*8 + (j-1)], a2);
        a3 = fmaf(s_kp[(e+3)*MTP + m], s_v[(e+3)*8 + (j-1)], a3);
      }
    }
    a.MOMP[(size_t)blockIdx.x*NMOM + tid] = (a0 + a1) + (a2 + a3);
  }
}

// grid: 288 + 144 + 72 + 36 = 540 blocks
// sb block ranges: sb0:[0,144) sb1:[144,288) sb2:[288,360) sb3:[360,432)
//                  sb4:[432,468) sb5:[468,504) sb6:[504,522) sb7:[522,540)
__global__ LB void qkvm_kernel(QkvmArgs a) {
  __shared__ __align__(16) float s_w[3072];
  __shared__ __align__(16) float s_sm[104];
  __shared__ __align__(16) float s_red[256*8];
  __shared__ __align__(16) float s_kp[64*MTP];
  __shared__ __align__(16) float s_v[64*8];
  const int bid = blockIdx.x;
  if (bid < 288)      qkvm_body<4> (a, 0, 9216, 0,     bid,     a.x0, a.w0, a.c0, s_w, s_sm, s_red, s_kp, s_v);
  else if (bid < 432) qkvm_body<8> (a, 1, 2304, 18432, bid-288, a.x1, a.w1, a.c1, s_w, s_sm, s_red, s_kp, s_v);
  else if (bid < 504) qkvm_body<16>(a, 2, 576,  23040, bid-432, a.x2, a.w2, a.c2, s_w, s_sm, s_red, s_kp, s_v);
  else                qkvm_body<32>(a, 3, 144,  24192, bid-504, a.x3, a.w3, a.c3, s_w, s_sm, s_red, s_kp, s_v);
}

// Reduce per-block partials: 8 sb x NSLICE row-slices = 32 blocks.
__global__ LB void momred_kernel(const float* __restrict__ MOMP, float* __restrict__ MOMQ) {
  const int sb = blockIdx.x / NSLICE, sl = blockIdx.x - sb*NSLICE;
  const int tid = threadIdx.x;
  if (tid >= NMOM) return;
  const int start[8] = {0, 144, 288, 360, 432, 468, 504, 522};
  const int cnt[8]   = {144, 144, 72, 72, 36, 36, 18, 18};
  const int r0 = start[sb] + (cnt[sb]*sl)/NSLICE;
  const int r1 = start[sb] + (cnt[sb]*(sl+1))/NSLICE;
  const float* bp = MOMP + (size_t)r0*NMOM + tid;
  const int c = r1 - r0;
  float a0=0.f,a1=0.f,a2=0.f,a3=0.f,a4=0.f,a5=0.f,a6=0.f,a7=0.f;
  int t = 0;
  for (; t + 8 <= c; t += 8) {
    a0 += bp[(size_t)(t+0)*NMOM];
    a1 += bp[(size_t)(t+1)*NMOM];
    a2 += bp[(size_t)(t+2)*NMOM];
    a3 += bp[(size_t)(t+3)*NMOM];
    a4 += bp[(size_t)(t+4)*NMOM];
    a5 += bp[(size_t)(t+5)*NMOM];
    a6 += bp[(size_t)(t+6)*NMOM];
    a7 += bp[(size_t)(t+7)*NMOM];
  }
  for (; t < c; ++t) a0 += bp[(size_t)t*NMOM];
  const float s = ((a0+a1)+(a2+a3)) + ((a4+a5)+(a6+a7));
  MOMQ[(size_t)blockIdx.x*NMOM + tid] = s;
}

struct FinArgs {
  const float *Q, *P, *MOMQ;
  const float *wg0, *bg0, *wg1, *bg1, *wg2, *bg2;
  float *Y;
};

// Per pixel: out[c] = (sum_m t_m M_m[c]) / (sum_m t_m d_m), t_m = q^m/m!; y = P + wg*out + bg.
__global__ LB void finish_kernel(FinArgs a) {
  __shared__ __align__(16) float smom[8*MT*12];   // 2688 floats, [sb][m][12]
  __shared__ float swg[3][64], sbg[3][8];
  const int tid = threadIdx.x;
  for (int i = tid; i < 8*MT*12; i += 256) smom[i] = 0.f;
  if (tid < 64) { swg[0][tid] = a.wg0[tid]; swg[1][tid] = a.wg1[tid]; swg[2][tid] = a.wg2[tid]; }
  if (tid < 8)  { sbg[0][tid] = a.bg0[tid]; sbg[1][tid] = a.bg1[tid]; sbg[2][tid] = a.bg2[tid]; }
  __syncthreads();
  for (int i = tid; i < 8*NMOM; i += 256) {
    const int sbi = i / NMOM, r = i - sbi*NMOM;
    const int m = r / 9, j = r - m*9;
    const float* qp = a.MOMQ + (size_t)sbi*NSLICE*NMOM + r;
    float s = 0.f;
    #pragma unroll
    for (int sl = 0; sl < NSLICE; ++sl) s += qp[(size_t)sl*NMOM];
    smom[sbi*(MT*12) + m*12 + j] = s;
  }
  __syncthreads();
  const int g = blockIdx.x*256 + tid;
  if (g >= NSLOT) return;
  int scale, N, off, widx;
  if (g < 18432)      { scale=0; N=9216; off=0;     widx=0; }
  else if (g < 23040) { scale=1; N=2304; off=18432; widx=1; }
  else if (g < 24192) { scale=2; N=576;  off=23040; widx=2; }
  else                { scale=3; N=144;  off=24192; widx=1; }  // scale3 uses cca1 (faithful)
  const int b = (g - off >= N) ? 1 : 0;
  const int sb = scale*2 + b;
  const float q = a.Q[g];
  const float* mb = &smom[sb*(MT*12)];
  float t = 1.f, den = 0.f;
  float num[8];
  #pragma unroll
  for (int c = 0; c < 8; ++c) num[c] = 0.f;
  #pragma unroll
  for (int m = 0; m < MT; ++m) {
    const f32x4 a0 = *(const f32x4*)&mb[m*12];
    const f32x4 a1 = *(const f32x4*)&mb[m*12 + 4];
    const f32x4 a2 = *(const f32x4*)&mb[m*12 + 8];
    den    = fmaf(t, a0.x, den);
    num[0] = fmaf(t, a0.y, num[0]); num[1] = fmaf(t, a0.z, num[1]); num[2] = fmaf(t, a0.w, num[2]);
    num[3] = fmaf(t, a1.x, num[3]); num[4] = fmaf(t, a1.y, num[4]); num[5] = fmaf(t, a1.z, num[5]);
    num[6] = fmaf(t, a1.w, num[6]); num[7] = fmaf(t, a2.x, num[7]);
    if (m + 1 < MT) t *= q * (1.f/(float)(m+1));   // unrolled -> constant folded
  }
  const float inv = 1.f/den;
  float o8[8];
  #pragma unroll
  for (int c = 0; c < 8; ++c) o8[c] = num[c]*inv;
  const f32x4 pA = *(const f32x4*)&a.P[(size_t)g*8];
  const f32x4 pB = *(const f32x4*)&a.P[(size_t)g*8 + 4];
  const float pv[8] = {pA.x, pA.y, pA.z, pA.w, pB.x, pB.y, pB.z, pB.w};
  const float* wg = swg[widx];
  float y[8];
  #pragma unroll
  for (int o = 0; o < 8; ++o) {
    float s2 = pv[o] + sbg[widx][o];
    #pragma unroll
    for (int c = 0; c < 8; ++c) s2 = fmaf(wg[o*8 + c], o8[c], s2);
    y[o] = s2;
  }
  f32x4* Yp = (f32x4*)&a.Y[(size_t)g*8];
  Yp[0] = (f32x4){y[0], y[1], y[2], y[3]};
  Yp[1] = (f32x4){y[4], y[5], y[6], y[7]};
}

template<int HS>
__device__ inline void bilerp8(float* zo, const float* Yb, int h, int w) {
  constexpr float inv = (float)HS/96.0f;
  const float sy = (h + 0.5f)*inv - 0.5f;
  const float sx = (w + 0.5f)*inv - 0.5f;
  const int iy0 = (int)floorf(sy); const float fy = sy - (float)iy0;
  const int ix0 = (int)floorf(sx); const float fx = sx - (float)ix0;
  const int y0 = min(max(iy0, 0), HS-1), y1 = min(max(iy0 + 1, 0), HS-1);
  const int x0 = min(max(ix0, 0), HS-1), x1 = min(max(ix0 + 1, 0), HS-1);
  const float* p00 = &Yb[(size_t)(y0*HS + x0)*8];
  const float* p01 = &Yb[(size_t)(y0*HS + x1)*8];
  const float* p10 = &Yb[(size_t)(y1*HS + x0)*8];
  const float* p11 = &Yb[(size_t)(y1*HS + x1)*8];
  const float w00 = (1.f-fy)*(1.f-fx), w01 = (1.f-fy)*fx, w10 = fy*(1.f-fx), w11 = fy*fx;
  #pragma unroll
  for (int c = 0; c < 8; ++c)
    zo[c] = w00*p00[c] + w01*p01[c] + w10*p10[c] + w11*p11[c];
}

// 256-thread blocks x 72; split fmaf chains; 19 static output accumulators.
__global__ LB void head_kernel(const float* __restrict__ Y,
                               const float* wl0, const float* bl0,
                               const float* bn_s, const float* bn_b,
                               const float* bn_m, const float* bn_v,
                               const float* wl1, const float* bl1,
                               float* __restrict__ out) {
  __shared__ float s_wl0[1024], s_wl1[608];
  __shared__ float s_bl0[32], s_sc[32], s_sh[32], s_bl1[19];
  const int tid = threadIdx.x;
  for (int i = tid; i < 1024; i += 256) s_wl0[i] = wl0[i];
  for (int i = tid; i < 608;  i += 256) s_wl1[i] = wl1[i];
  if (tid < 32) {
    s_bl0[tid] = bl0[tid];
    const float sc = bn_s[tid] / sqrtf(bn_v[tid] + 1e-5f);
    s_sc[tid] = sc;
    s_sh[tid] = bn_b[tid] - bn_m[tid]*sc;
  }
  if (tid >= 32 && tid < 51) s_bl1[tid - 32] = bl1[tid - 32];
  __syncthreads();
  const int gp = blockIdx.x*256 + tid;   // exactly 18432 threads
  const int b = (gp >= 9216) ? 1 : 0;
  const int n = gp - b*9216;
  const int h = n / 96, w = n - h*96;
  float z[32];
  {
    const float4 zA = *(const float4*)&Y[(size_t)(b*9216 + n)*8];
    const float4 zB = *(const float4*)&Y[(size_t)(b*9216 + n)*8 + 4];
    z[0]=zA.x; z[1]=zA.y; z[2]=zA.z; z[3]=zA.w; z[4]=zB.x; z[5]=zB.y; z[6]=zB.z; z[7]=zB.w;
  }
  bilerp8<48>(z + 8,  &Y[(size_t)(18432 + b*2304)*8], h, w);
  bilerp8<24>(z + 16, &Y[(size_t)(23040 + b*576)*8],  h, w);
  bilerp8<12>(z + 24, &Y[(size_t)(24192 + b*144)*8],  h, w);
  float o19[19];
  #pragma unroll
  for (int j = 0; j < 19; ++j) o19[j] = s_bl1[j];
  #pragma unroll 1
  for (int o = 0; o < 32; ++o) {
    float sA = s_bl0[o], sB = 0.f;   // two chains halve the dependency stall
    #pragma unroll
    for (int c4 = 0; c4 < 4; ++c4) {
      const float4 wv = *(const float4*)&s_wl0[o*32 + c4*4];
      sA = fmaf(wv.x, z[c4*4+0], sA);
      sA = fmaf(wv.y, z[c4*4+1], sA);
      sA = fmaf(wv.z, z[c4*4+2], sA);
      sA = fmaf(wv.w, z[c4*4+3], sA);
    }
    #pragma unroll
    for (int c4 = 4; c4 < 8; ++c4) {
      const float4 wv = *(const float4*)&s_wl0[o*32 + c4*4];
      sB = fmaf(wv.x, z[c4*4+0], sB);
      sB = fmaf(wv.y, z[c4*4+1], sB);
      sB = fmaf(wv.z, z[c4*4+2], sB);
      sB = fmaf(wv.w, z[c4*4+3], sB);
    }
    const float t = fmaxf(fmaf(sA + sB, s_sc[o], s_sh[o]), 0.f);
    #pragma unroll
    for (int j = 0; j < 19; ++j) o19[j] = fmaf(s_wl1[j*32 + o], t, o19[j]);
  }
  #pragma unroll
  for (int j = 0; j < 19; ++j)
    out[((size_t)b*19 + j)*9216 + n] = o19[j];
}

extern "C" void kernel_launch(void* const* d_in, const int* in_sizes, int n_in,
                              void* d_out, int out_size, void* d_ws, size_t ws_size,
                              hipStream_t stream) {
  (void)in_sizes; (void)n_in; (void)out_size; (void)ws_size;
  const float* wq[3]; const float* bq[3]; const float* wk[3]; const float* bk[3];
  const float* wv[3]; const float* bv[3]; const float* wg[3]; const float* bg[3];
  for (int i = 0; i < 3; ++i) {
    const int base = 12 + i*8;
    wq[i] = (const float*)d_in[base + 0]; bq[i] = (const float*)d_in[base + 1];
    wk[i] = (const float*)d_in[base + 2]; bk[i] = (const float*)d_in[base + 3];
    wv[i] = (const float*)d_in[base + 4]; bv[i] = (const float*)d_in[base + 5];
    wg[i] = (const float*)d_in[base + 6]; bg[i] = (const float*)d_in[base + 7];
  }
  const int m4[4] = {0, 1, 2, 1};   // scale -> cca index (scale3 reuses cca1, faithful)

  // workspace (floats): P[8N] Q[N] MOMP[540*252] MOMQ[32*252] Y[8N]  (~2.3 MB)
  float* ws = (float*)d_ws;
  float* P = ws;
  float* Q = P + (size_t)NSLOT*8;
  float* MOMP = Q + NSLOT;
  float* MOMQ = MOMP + (size_t)NBLK_Q*NMOM;
  float* Y = MOMQ + (size_t)8*NSLICE*NMOM;

  QkvmArgs qa;
  qa.x0 = (const float*)d_in[0]; qa.x1 = (const float*)d_in[1];
  qa.x2 = (const float*)d_in[2]; qa.x3 = (const float*)d_in[3];
  qa.w0 = (const float*)d_in[4];  qa.c0 = (const float*)d_in[5];
  qa.w1 = (const float*)d_in[6];  qa.c1 = (const float*)d_in[7];
  qa.w2 = (const float*)d_in[8];  qa.c2 = (const float*)d_in[9];
  qa.w3 = (const float*)d_in[10]; qa.c3 = (const float*)d_in[11];
  for (int s = 0; s < 4; ++s) {
    qa.wq[s] = wq[m4[s]]; qa.bq[s] = bq[m4[s]];
    qa.wk[s] = wk[m4[s]]; qa.bk[s] = bk[m4[s]];
    qa.wv[s] = wv[m4[s]]; qa.bv[s] = bv[m4[s]];
  }
  qa.P = P; qa.Q = Q; qa.MOMP = MOMP;

  FinArgs fa;
  fa.Q = Q; fa.P = P; fa.MOMQ = MOMQ;
  fa.wg0 = wg[0]; fa.bg0 = bg[0];
  fa.wg1 = wg[1]; fa.bg1 = bg[1];
  fa.wg2 = wg[2]; fa.bg2 = bg[2];
  fa.Y = Y;

  qkvm_kernel<<<NBLK_Q, 256, 0, stream>>>(qa);
  momred_kernel<<<8*NSLICE, 256, 0, stream>>>(MOMP, MOMQ);
  finish_kernel<<<96, 256, 0, stream>>>(fa);
  head_kernel<<<72, 256, 0, stream>>>(Y, (const float*)d_in[36], (const float*)d_in[37],
                                      (const float*)d_in[38], (const float*)d_in[39],
                                      (const float*)d_in[40], (const float*)d_in[41],
                                      (const float*)d_in[42], (const float*)d_in[43],
                                      (float*)d_out);
}